// Round 3
// baseline (472.299 us; speedup 1.0000x reference)
//
#include <hip/hip_runtime.h>
#include <hip/hip_bf16.h>
#include <stdint.h>

using sh8    = __attribute__((ext_vector_type(8))) short;
using f32x4  = __attribute__((ext_vector_type(4))) float;
using f32x16 = __attribute__((ext_vector_type(16))) float;

#define MFMA16(a, b, c) __builtin_amdgcn_mfma_f32_16x16x32_bf16(a, b, c, 0, 0, 0)
#define EXP2F(x) __builtin_amdgcn_exp2f(x)
#define SBAR()  __builtin_amdgcn_s_barrier()
#define CFENCE() asm volatile("" ::: "memory")

static constexpr int BB = 32, SS = 577, HH = 16;
static constexpr int MM = BB * SS;     // 18464 rows (b,s)
static constexpr int SPAD = 640;       // padded S for V^T buffer
// attention scale folded into Wq, in log2 domain: D^-0.5 * log2(e)
static constexpr float QSCALE = 0.18033688011112042f;

__device__ __forceinline__ ushort f2b(float f) {
  union { float f; uint32_t u; } v{f};
  uint32_t r = v.u + 0x7FFFu + ((v.u >> 16) & 1u);   // RNE
  return (ushort)(r >> 16);
}

#if __has_builtin(__builtin_amdgcn_cvt_pk_bf16_f32)
typedef __attribute__((ext_vector_type(2))) __bf16 bf16x2_t;
__device__ __forceinline__ uint32_t pk_bf16(float a, float b) {
  union { bf16x2_t v; uint32_t u; } c;
  c.v = __builtin_amdgcn_cvt_pk_bf16_f32(a, b);
  return c.u;
}
#else
__device__ __forceinline__ uint32_t pk_bf16(float a, float b) {
  return (uint32_t)f2b(a) | ((uint32_t)f2b(b) << 16);
}
#endif

// async global->LDS, 16B per lane. LDS dest is wave-uniform base + lane*16.
__device__ __forceinline__ void gld16(const ushort* g, ushort* l) {
  __builtin_amdgcn_global_load_lds(
      (const __attribute__((address_space(1))) uint32_t*)g,
      (__attribute__((address_space(3))) uint32_t*)l, 16, 0, 0);
}

// ---------------- converts (x and Wo fused in one launch) ----------------
__global__ __launch_bounds__(256)
void convert2_f32_bf16(const float* __restrict__ a, ushort* __restrict__ oa, int na4,
                       const float* __restrict__ b, ushort* __restrict__ ob, int nb4) {
  const int total = na4 + nb4;
  const int stride = gridDim.x * 256;
  for (int i = blockIdx.x * 256 + threadIdx.x; i < total; i += stride) {
    const float4 f = (i < na4) ? ((const float4*)a)[i] : ((const float4*)b)[i - na4];
    ushort4 u;
    u.x = f2b(f.x); u.y = f2b(f.y); u.z = f2b(f.z); u.w = f2b(f.w);
    if (i < na4) ((ushort4*)oa)[i] = u;
    else         ((ushort4*)ob)[i - na4] = u;
  }
}

// Wt[n][k], n = sel*1024 + h*64 + d  (B^T layout), k = e.  LDS-tiled transpose.
// Wq gets QSCALE folded in. grid (16 ktiles, 48 sel*h).
__global__ __launch_bounds__(256)
void convert_wqkv(const float* __restrict__ Wq, const float* __restrict__ Wk,
                  const float* __restrict__ Wv, ushort* __restrict__ Wt) {
  __shared__ ushort T[64 * 72];
  const int tid = threadIdx.x;
  const int kt = blockIdx.x, sh = blockIdx.y;
  const int sel = sh >> 4, h = sh & 15;
  const float* W = (sel == 0) ? Wq : ((sel == 1) ? Wk : Wv);
  const float qs = (sel == 0) ? QSCALE : 1.0f;
  const int rr = tid >> 4;          // 0..15 (k' row)
  const int rc = (tid & 15) * 4;    // d col (float4)
#pragma unroll
  for (int p = 0; p < 64; p += 16) {
    const float4 f = *(const float4*)(W + (size_t)h * 65536 + (size_t)(kt * 64 + p + rr) * 64 + rc);
    ushort4 u;
    u.x = f2b(f.x * qs); u.y = f2b(f.y * qs); u.z = f2b(f.z * qs); u.w = f2b(f.w * qs);
    *(ushort4*)&T[(p + rr) * 72 + rc] = u;
  }
  __syncthreads();
  const int dd = tid >> 2;          // 0..63 (d)
  const int c16 = (tid & 3) * 16;   // k' base
  sh8 v0, v1;
#pragma unroll
  for (int j = 0; j < 8; j++) v0[j] = (short)T[(c16 + j) * 72 + dd];
#pragma unroll
  for (int j = 0; j < 8; j++) v1[j] = (short)T[(c16 + 8 + j) * 72 + dd];
  ushort* op = Wt + ((size_t)sel * 1024 + h * 64 + dd) * 1024 + kt * 64 + c16;
  *(sh8*)op = v0;
  *(sh8*)(op + 8) = v1;
}

// ---------------- GEMM: 256x256 block, 8 waves (2x4), wave tile 128x64,
// BK=64, MFMA 16x16x32 (16-row fragment reads -> 2-way LDS aliasing = free;
// the 32x32 variant's 32-row reads are structurally >=4-way conflicted),
// double-buffered LDS, ONE vmcnt(0)+s_barrier per K-tile, full-unroll body so
// the compiler interleaves ds_read_b128 with MFMA via counted lgkmcnt.
// Staging for tile t+1 issues at the top of tile t (issue->wait distance =
// one full tile >> HBM latency). XOR-swizzled LDS (both-sides, rule 21),
// XCD-bijective block swizzle (m204). K fixed 1024. C^T fragment trick.
// MODE 0: store bf16.  MODE 1: store f32 + bias.
template <int MODE>
__global__ __launch_bounds__(512, 2)
void gemm256(const ushort* __restrict__ A, const ushort* __restrict__ Bt,
             ushort* __restrict__ Cb, float* __restrict__ Cf,
             const float* __restrict__ bias, int N) {
  constexpr int K = 1024;
  constexpr int NT = K / 64;             // 16 K-tiles
  __shared__ ushort Al[2][256 * 64];     // 64 KB (double-buffered A tile)
  __shared__ ushort Bl[2][256 * 64];     // 64 KB (double-buffered B tile)
  const int tid = threadIdx.x;
  const int lane = tid & 63;
  const int w = tid >> 6;                // 0..7
  const int l15 = lane & 15, quad = lane >> 4;
  const int wm = (w >> 2) * 128;         // WARPS_M = 2
  const int wn = (w & 3) * 64;           // WARPS_N = 4

  // XCD-bijective swizzle (nwg % 8 != 0 here, so m204 form required)
  const int nwg = gridDim.x * gridDim.y;
  const int orig = blockIdx.y * gridDim.x + blockIdx.x;
  const int q = nwg >> 3, r = nwg & 7;
  const int xcd = orig & 7, loc = orig >> 3;
  const int wgid = (xcd < r ? xcd * (q + 1) : r * (q + 1) + (xcd - r) * q) + loc;
  const int m0 = (wgid / gridDim.x) * 256;
  const int n0 = (wgid % gridDim.x) * 256;

  f32x4 acc[8][4];
#pragma unroll
  for (int i = 0; i < 8; i++)
#pragma unroll
    for (int j = 0; j < 4; j++) acc[i][j] = f32x4{0.f, 0.f, 0.f, 0.f};

  // staging: unit = 64 rows x 64 cols (8 KB) = 1 gld16 per thread.
  // thread (r9 = tid>>3, c = tid&7) stores linearly at LDS chunk c of row r9,
  // fetches pre-swizzled global chunk c ^ (r9&7)  (both-sides swizzle, rule 21).
  const int r9 = tid >> 3;                       // 0..63
  const int cs = ((tid & 7) ^ (r9 & 7)) * 8;     // swizzled source chunk (ushorts)
  const ushort* Asrc[4];
  const ushort* Bsrc[4];
#pragma unroll
  for (int i = 0; i < 4; i++) {
    Asrc[i] = A + (size_t)min(m0 + i * 64 + r9, MM - 1) * K + cs;
    Bsrc[i] = Bt + (size_t)(n0 + i * 64 + r9) * K + cs;
  }
  ushort* dA = &Al[0][0] + tid * 8;              // + b*16384 + i*4096
  ushort* dB = &Bl[0][0] + tid * 8;

#define STAGE(b, ko)                                              \
  do {                                                            \
    _Pragma("unroll")                                             \
    for (int i_ = 0; i_ < 4; i_++) {                              \
      gld16(Asrc[i_] + (ko), dA + (b) * 16384 + i_ * 4096);       \
      gld16(Bsrc[i_] + (ko), dB + (b) * 16384 + i_ * 4096);       \
    }                                                             \
  } while (0)

  // frag-read offsets: global chunk g of row r lives at LDS chunk g ^ (r&7).
  // 16x16x32 fragment: lane (l15,quad) reads row base+l15 (16-row span),
  // k-chunk kc: logical chunk = kc*4 + quad.  row&7 == l15&7 (16 | strides).
  const int swz = l15 & 7;
  const int c0 = (quad ^ swz) * 8;               // kc=0: k = quad*8 + 0..7
  const int c1 = ((quad + 4) ^ swz) * 8;         // kc=1: k = 32 + quad*8 + 0..7
  const int arow = (wm + l15) * 64;              // + i*1024 per 16-row m-pos
  const int brow = (wn + l15) * 64;              // + j*1024 per 16-row n-pos

  // prologue: stage tile 0, publish
  STAGE(0, 0);
  asm volatile("s_waitcnt vmcnt(0)" ::: "memory");
  SBAR();
  CFENCE();

  for (int t = 0; t < NT; ++t) {
    const ushort* Ab = &Al[t & 1][0];
    const ushort* Bb = &Bl[t & 1][0];
    // issue next tile's staging first: overlaps this whole tile's compute,
    // lands long before the boundary vmcnt(0).
    if (t < NT - 1) STAGE((t + 1) & 1, (t + 1) * 64);

    // tile body: 24 ds_read_b128 + 64 MFMA16, fully unrolled, no inner
    // barriers; compiler interleaves via counted lgkmcnt (m97 behavior).
#pragma unroll
    for (int kc = 0; kc < 2; kc++) {
      const int ck = (kc == 0) ? c0 : c1;
      sh8 af[8], bfr[4];
#pragma unroll
      for (int i = 0; i < 8; i++) af[i] = *(const sh8*)(Ab + arow + i * 1024 + ck);
#pragma unroll
      for (int j = 0; j < 4; j++) bfr[j] = *(const sh8*)(Bb + brow + j * 1024 + ck);
      // C^T: D[m=Ccol][n=Crow]; A-op = B-tile frag, B-op = A-tile frag
#pragma unroll
      for (int i = 0; i < 8; i++)
#pragma unroll
        for (int j = 0; j < 4; j++) acc[i][j] = MFMA16(bfr[j], af[i], acc[i][j]);
    }

    if (t < NT - 1) {
      // own next-tile loads landed (issued one full tile ago)...
      asm volatile("s_waitcnt vmcnt(0)" ::: "memory");
      // ...then publish across waves; all frag reads of this tile were
      // consumed by MFMAs (hence retired) before this barrier.
      SBAR();
      CFENCE();
    }
  }
#undef STAGE

  // C^T epilogue (16x16 C/D map: col=lane&15, row=(lane>>4)*4+reg):
  // lane holds C-row = m0+wm+i*16+l15; C-cols = n0+wn+j*16 + quad*4 + 0..3
#pragma unroll
  for (int i = 0; i < 8; i++) {
    const int row = m0 + wm + i * 16 + l15;
    const bool ok = row < MM;
#pragma unroll
    for (int j = 0; j < 4; j++) {
      const int col0 = n0 + wn + j * 16 + quad * 4;
      if (MODE == 0) {
        uint2 pk;
        pk.x = pk_bf16(acc[i][j][0], acc[i][j][1]);
        pk.y = pk_bf16(acc[i][j][2], acc[i][j][3]);
        if (ok) *(uint2*)&Cb[(size_t)row * N + col0] = pk;
      } else {
        const float4 b4 = *(const float4*)&bias[col0];
        float4 v;
        v.x = acc[i][j][0] + b4.x; v.y = acc[i][j][1] + b4.y;
        v.z = acc[i][j][2] + b4.z; v.w = acc[i][j][3] + b4.w;
        if (ok) *(float4*)&Cf[(size_t)row * N + col0] = v;
      }
    }
  }
}

// ---------------- transpose V: QKV[.,2048+h*64+d] -> Vt[(bh*64+d)][s], zero-padded ----------------
__global__ __launch_bounds__(256)
void transpose_v(const ushort* __restrict__ QKV, ushort* __restrict__ Vtg) {
  __shared__ ushort T[64 * 72];
  const int tid = threadIdx.x;
  const int st = blockIdx.x, bh = blockIdx.y;
  const int b = bh >> 4, h = bh & 15;
  const int sr = tid >> 3;          // 0..31
  const int sc = (tid & 7) * 8;     // d-chunk
#pragma unroll
  for (int p = 0; p < 64; p += 32) {
    const int s = st * 64 + p + sr;
    uint4 d = uint4{0u, 0u, 0u, 0u};
    if (s < SS) d = *(const uint4*)(QKV + ((size_t)b * SS + s) * 3072 + 2048 + h * 64 + sc);
    *(uint4*)&T[(p + sr) * 72 + sc] = d;
  }
  __syncthreads();
  const int dd = tid >> 2;          // 0..63
  const int s16 = (tid & 3) * 16;
  sh8 v0, v1;
#pragma unroll
  for (int j = 0; j < 8; j++) v0[j] = (short)T[(s16 + j) * 72 + dd];
#pragma unroll
  for (int j = 0; j < 8; j++) v1[j] = (short)T[(s16 + 8 + j) * 72 + dd];
  ushort* outp = Vtg + ((size_t)bh * 64 + dd) * SPAD + st * 64 + s16;
  *(sh8*)outp = v0;
  *(sh8*)(outp + 8) = v1;
}

// ---------------- flash attention (one-pass softmax, 32 q-rows/wave) -------------
// grid: (5 qblocks of 128, 512 bh). K/V staged via gld16 into swizzled 64-stride
// tiles; each wave reuses K/V frags across 2 q-groups of 16.
// S^T = K·Q^T; O^T = V^T·P^T; l = ones·P^T (all MFMA, no shuffles).
__global__ __launch_bounds__(256)
void flash_attn(const ushort* __restrict__ QKV, const ushort* __restrict__ Vtg,
                ushort* __restrict__ Ob) {
  __shared__ ushort Kl[64 * 64];    // row = kpos, chunk-swizzled
  __shared__ ushort Vl[64 * 64];    // row = d,    chunk-swizzled
  __shared__ ushort Pl[128 * 72];   // row = q (wave-local 32 rows), col = kpos
  const int tid = threadIdx.x;
  const int lane = tid & 63, w = tid >> 6;
  const int l15 = lane & 15, quad = lane >> 4;
  const int qb = blockIdx.x, bh = blockIdx.y;
  const int b = bh >> 4, h = bh & 15;

  sh8 qf[2][2];
#pragma unroll
  for (int g = 0; g < 2; g++) {
    const int qr = qb * 128 + w * 32 + g * 16 + l15;
    const ushort* qrow = QKV + ((size_t)b * SS + min(qr, SS - 1)) * 3072 + h * 64;
    qf[g][0] = *(const sh8*)(qrow + quad * 8);
    qf[g][1] = *(const sh8*)(qrow + 32 + quad * 8);
  }

  sh8 ones;
#pragma unroll
  for (int j = 0; j < 8; j++) ones[j] = (short)0x3F80;   // bf16 1.0

  f32x4 o[2][4];
  f32x4 acc_l[2];
#pragma unroll
  for (int g = 0; g < 2; g++) {
    acc_l[g] = f32x4{0.f, 0.f, 0.f, 0.f};
#pragma unroll
    for (int t = 0; t < 4; t++) o[g][t] = f32x4{0.f, 0.f, 0.f, 0.f};
  }

  // staging: 2 gld16 per matrix; unit u = i*256+tid, row=u>>3, cc=u&7, swizzled source
  const int r0 = tid >> 3;                           // 0..31
  const int swzs = ((tid & 7) ^ (r0 & 7)) * 8;
  const ushort* Kg = QKV + (size_t)b * SS * 3072 + 1024 + h * 64 + swzs;
  const ushort* Vg0 = Vtg + ((size_t)bh * 64 + r0) * SPAD + swzs;
  const ushort* Vg1 = Vtg + ((size_t)bh * 64 + 32 + r0) * SPAD + swzs;
  ushort* lK0 = &Kl[tid * 8];
  ushort* lK1 = &Kl[(256 + tid) * 8];
  ushort* lV0 = &Vl[tid * 8];
  ushort* lV1 = &Vl[(256 + tid) * 8];

  const int swz = l15 & 7;
  const int ca0 = (quad ^ swz) * 8;
  const int ca1 = ((quad + 4) ^ swz) * 8;
  ushort* plw[2] = { &Pl[(w * 32 + l15) * 72], &Pl[(w * 32 + 16 + l15) * 72] };

  for (int kt = 0; kt < 10; kt++) {
    const int kb = kt * 64;
    __syncthreads();
    gld16(Kg + (size_t)min(kb + r0, SS - 1) * 3072, lK0);
    gld16(Kg + (size_t)min(kb + 32 + r0, SS - 1) * 3072, lK1);
    gld16(Vg0 + kb, lV0);
    gld16(Vg1 + kb, lV1);
    __syncthreads();

#pragma unroll
    for (int tn = 0; tn < 4; tn++) {
      const int kr = tn * 16 + l15;
      const sh8 k0 = *(const sh8*)&Kl[kr * 64 + ca0];
      const sh8 k1 = *(const sh8*)&Kl[kr * 64 + ca1];
#pragma unroll
      for (int g = 0; g < 2; g++) {
        f32x4 s = f32x4{0.f, 0.f, 0.f, 0.f};
        s = MFMA16(k0, qf[g][0], s);      // S^T: row=kpos=tn*16+quad*4+r, col=q=l15
        s = MFMA16(k1, qf[g][1], s);
        if (kt == 9) {                    // kb=576: only kpos-local 0 is valid
#pragma unroll
          for (int r = 0; r < 4; r++)
            if ((tn * 16 + quad * 4 + r) != 0) s[r] = -1e30f;
        }
        uint2 pp;
        pp.x = pk_bf16(EXP2F(s[0]), EXP2F(s[1]));
        pp.y = pk_bf16(EXP2F(s[2]), EXP2F(s[3]));
        *(uint2*)(plw[g] + tn * 16 + quad * 4) = pp;
      }
    }
    // wave-local P rows: no barrier needed between write and read
    sh8 pa[2][2];
#pragma unroll
    for (int g = 0; g < 2; g++) {
      pa[g][0] = *(const sh8*)(plw[g] + quad * 8);     // B: n=q=l15, k=kpos
      pa[g][1] = *(const sh8*)(plw[g] + 32 + quad * 8);
      acc_l[g] = MFMA16(ones, pa[g][0], acc_l[g]);
      acc_l[g] = MFMA16(ones, pa[g][1], acc_l[g]);
    }
#pragma unroll
    for (int t = 0; t < 4; t++) {
      const int vr = t * 16 + l15;
      const sh8 v0 = *(const sh8*)&Vl[vr * 64 + ca0];  // A: m=d, k=kpos
      const sh8 v1 = *(const sh8*)&Vl[vr * 64 + ca1];
#pragma unroll
      for (int g = 0; g < 2; g++) {
        o[g][t] = MFMA16(v0, pa[g][0], o[g][t]);       // O^T: row=d, col=q=l15
        o[g][t] = MFMA16(v1, pa[g][1], o[g][t]);
      }
    }
  }

#pragma unroll
  for (int g = 0; g < 2; g++) {
    const float inv = 1.0f / acc_l[g][0];
    const int s = qb * 128 + w * 32 + g * 16 + l15;
    if (s < SS) {
      ushort* op = Ob + ((size_t)b * SS + s) * 1024 + h * 64 + quad * 4;
#pragma unroll
      for (int t = 0; t < 4; t++) {
        uint2 ov;
        ov.x = pk_bf16(o[g][t][0] * inv, o[g][t][1] * inv);
        ov.y = pk_bf16(o[g][t][2] * inv, o[g][t][3] * inv);
        *(uint2*)(op + t * 16) = ov;
      }
    }
  }
}

// ---------------- launch ----------------
extern "C" void kernel_launch(void* const* d_in, const int* in_sizes, int n_in,
                              void* d_out, int out_size, void* d_ws, size_t ws_size,
                              hipStream_t stream) {
  const float* x  = (const float*)d_in[0];
  const float* Wq = (const float*)d_in[1];
  const float* Wk = (const float*)d_in[2];
  const float* Wv = (const float*)d_in[3];
  const float* Wo = (const float*)d_in[4];
  const float* bo = (const float*)d_in[5];
  float* out = (float*)d_out;

  // workspace layout (bf16 elements); Ob reuses Xb (dead after GEMM1)
  ushort* Xb  = (ushort*)d_ws;                      // MM*1024
  ushort* Wt  = Xb  + (size_t)MM * 1024;            // 3072*1024
  ushort* Wob = Wt  + (size_t)3072 * 1024;          // 1024*1024
  ushort* QKV = Wob + (size_t)1024 * 1024;          // MM*3072
  ushort* Vtg = QKV + (size_t)MM * 3072;            // 512*64*640
  ushort* Ob  = Xb;

  convert2_f32_bf16<<<4096, 256, 0, stream>>>(x, Xb, MM * 1024 / 4, Wo, Wob, 1024 * 1024 / 4);
  convert_wqkv<<<dim3(16, 48), 256, 0, stream>>>(Wq, Wk, Wv, Wt);
  gemm256<0><<<dim3(12, 73), 512, 0, stream>>>(Xb, Wt, QKV, nullptr, nullptr, 3072);
  transpose_v<<<dim3(10, 512), 256, 0, stream>>>(QKV, Vtg);
  flash_attn<<<dim3(5, 512), 256, 0, stream>>>(QKV, Vtg, Ob);
  gemm256<1><<<dim3(4, 73), 512, 0, stream>>>(Ob, Wob, nullptr, out, bo, 1024);
}

// Round 4
// 457.297 us; speedup vs baseline: 1.0328x; 1.0328x over previous
//
#include <hip/hip_runtime.h>
#include <hip/hip_bf16.h>
#include <stdint.h>

using sh8    = __attribute__((ext_vector_type(8))) short;
using f32x4  = __attribute__((ext_vector_type(4))) float;
using f32x16 = __attribute__((ext_vector_type(16))) float;

#define MFMA16(a, b, c) __builtin_amdgcn_mfma_f32_16x16x32_bf16(a, b, c, 0, 0, 0)
#define EXP2F(x) __builtin_amdgcn_exp2f(x)

static constexpr int BB = 32, SS = 577, HH = 16;
static constexpr int MM = BB * SS;     // 18464 rows (b,s)
static constexpr int SPAD = 640;       // padded S for V^T buffer
// attention scale folded into Wq, in log2 domain: D^-0.5 * log2(e)
static constexpr float QSCALE = 0.18033688011112042f;

__device__ __forceinline__ ushort f2b(float f) {
  union { float f; uint32_t u; } v{f};
  uint32_t r = v.u + 0x7FFFu + ((v.u >> 16) & 1u);   // RNE
  return (ushort)(r >> 16);
}

#if __has_builtin(__builtin_amdgcn_cvt_pk_bf16_f32)
typedef __attribute__((ext_vector_type(2))) __bf16 bf16x2_t;
__device__ __forceinline__ uint32_t pk_bf16(float a, float b) {
  union { bf16x2_t v; uint32_t u; } c;
  c.v = __builtin_amdgcn_cvt_pk_bf16_f32(a, b);
  return c.u;
}
#else
__device__ __forceinline__ uint32_t pk_bf16(float a, float b) {
  return (uint32_t)f2b(a) | ((uint32_t)f2b(b) << 16);
}
#endif

// async global->LDS, 16B per lane. LDS dest is wave-uniform base + lane*16.
__device__ __forceinline__ void gld16(const ushort* g, ushort* l) {
  __builtin_amdgcn_global_load_lds(
      (const __attribute__((address_space(1))) uint32_t*)g,
      (__attribute__((address_space(3))) uint32_t*)l, 16, 0, 0);
}

// ---------------- converts (x and Wo fused in one launch) ----------------
__global__ __launch_bounds__(256)
void convert2_f32_bf16(const float* __restrict__ a, ushort* __restrict__ oa, int na4,
                       const float* __restrict__ b, ushort* __restrict__ ob, int nb4) {
  const int total = na4 + nb4;
  const int stride = gridDim.x * 256;
  for (int i = blockIdx.x * 256 + threadIdx.x; i < total; i += stride) {
    const float4 f = (i < na4) ? ((const float4*)a)[i] : ((const float4*)b)[i - na4];
    ushort4 u;
    u.x = f2b(f.x); u.y = f2b(f.y); u.z = f2b(f.z); u.w = f2b(f.w);
    if (i < na4) ((ushort4*)oa)[i] = u;
    else         ((ushort4*)ob)[i - na4] = u;
  }
}

// Wt[n][k], n = sel*1024 + h*64 + d  (B^T layout), k = e.  LDS-tiled transpose.
// Wq gets QSCALE folded in. grid (16 ktiles, 48 sel*h).
__global__ __launch_bounds__(256)
void convert_wqkv(const float* __restrict__ Wq, const float* __restrict__ Wk,
                  const float* __restrict__ Wv, ushort* __restrict__ Wt) {
  __shared__ ushort T[64 * 72];
  const int tid = threadIdx.x;
  const int kt = blockIdx.x, sh = blockIdx.y;
  const int sel = sh >> 4, h = sh & 15;
  const float* W = (sel == 0) ? Wq : ((sel == 1) ? Wk : Wv);
  const float qs = (sel == 0) ? QSCALE : 1.0f;
  const int rr = tid >> 4;          // 0..15 (k' row)
  const int rc = (tid & 15) * 4;    // d col (float4)
#pragma unroll
  for (int p = 0; p < 64; p += 16) {
    const float4 f = *(const float4*)(W + (size_t)h * 65536 + (size_t)(kt * 64 + p + rr) * 64 + rc);
    ushort4 u;
    u.x = f2b(f.x * qs); u.y = f2b(f.y * qs); u.z = f2b(f.z * qs); u.w = f2b(f.w * qs);
    *(ushort4*)&T[(p + rr) * 72 + rc] = u;
  }
  __syncthreads();
  const int dd = tid >> 2;          // 0..63 (d)
  const int c16 = (tid & 3) * 16;   // k' base
  sh8 v0, v1;
#pragma unroll
  for (int j = 0; j < 8; j++) v0[j] = (short)T[(c16 + j) * 72 + dd];
#pragma unroll
  for (int j = 0; j < 8; j++) v1[j] = (short)T[(c16 + 8 + j) * 72 + dd];
  ushort* op = Wt + ((size_t)sel * 1024 + h * 64 + dd) * 1024 + kt * 64 + c16;
  *(sh8*)op = v0;
  *(sh8*)(op + 8) = v1;
}

// ---------------- GEMM: 128x128 block, 4 waves, 64x64 wave tile as 4x4 grid
// of 16x16x32 MFMA (16-row fragment reads -> 2-way LDS aliasing = free; the
// previous 32x32x16 fragments' 32-row reads were >=4-way bank-conflicted:
// 1.43e7 SQ_LDS_BANK_CONFLICT -> ~0). m97 2-barrier schedule, 32 KB LDS,
// multi-block/CU residency for inter-block latency hiding (m114). C^T trick.
// MODE 0: store bf16.  MODE 1: store f32 + bias.
template <int MODE>
__global__ __launch_bounds__(256)
void gemm_bt(const ushort* __restrict__ A, const ushort* __restrict__ Bt,
             ushort* __restrict__ Cb, float* __restrict__ Cf,
             const float* __restrict__ bias, int M, int N, int K) {
  __shared__ ushort Al[128 * 64];   // 16 KB
  __shared__ ushort Bl[128 * 64];   // 16 KB
  const int tid = threadIdx.x;
  const int lane = tid & 63, w = tid >> 6;
  const int l15 = lane & 15, quad = lane >> 4;
  const int wm = (w >> 1) * 64, wn = (w & 1) * 64;
  const int m0 = blockIdx.y * 128, n0 = blockIdx.x * 128;

  f32x4 acc[4][4];
#pragma unroll
  for (int i = 0; i < 4; i++)
#pragma unroll
    for (int j = 0; j < 4; j++) acc[i][j] = f32x4{0.f, 0.f, 0.f, 0.f};

  // staging: unit u covers LDS ushorts [u*8, u*8+8); row=u>>3, cc=u&7 (swizzled)
  const int rbase = tid >> 3;                         // 0..31
  const int swzc = ((tid & 7) ^ (rbase & 7)) * 8;     // swizzled source col (ushorts)
  const ushort* Ag[4]; const ushort* Bg[4];
  ushort* lA[4]; ushort* lB[4];
#pragma unroll
  for (int i = 0; i < 4; i++) {
    Ag[i] = A + (size_t)min(m0 + i * 32 + rbase, M - 1) * K + swzc;
    Bg[i] = Bt + (size_t)(n0 + i * 32 + rbase) * K + swzc;
    lA[i] = &Al[(i * 256 + tid) * 8];
    lB[i] = &Bl[(i * 256 + tid) * 8];
  }
  // frag-read offsets: global chunk g of row r lives at LDS chunk g ^ (r&7).
  // 16x16x32 fragment: lane (l15,quad) reads row base+l15 (16-row span, 2-way
  // bank aliasing = free), k-chunk kc: logical chunk = kc*4 + quad.
  const int swz = l15 & 7;
  const int c0 = (quad ^ swz) * 8;               // kc=0: k = quad*8 + 0..7
  const int c1 = ((quad + 4) ^ swz) * 8;         // kc=1: k = 32 + quad*8 + 0..7
  const int arow = (wm + l15) * 64;              // + i*1024 per 16-row m-pos
  const int brow = (wn + l15) * 64;              // + j*1024 per 16-row n-pos

  for (int k0 = 0; k0 < K; k0 += 64) {
    __syncthreads();
#pragma unroll
    for (int i = 0; i < 4; i++) {
      gld16(Ag[i] + k0, lA[i]);
      gld16(Bg[i] + k0, lB[i]);
    }
    __syncthreads();
#pragma unroll
    for (int kc = 0; kc < 2; kc++) {
      const int ck = (kc == 0) ? c0 : c1;
      sh8 af[4], bfr[4];
#pragma unroll
      for (int i = 0; i < 4; i++) af[i] = *(const sh8*)&Al[arow + i * 1024 + ck];
#pragma unroll
      for (int j = 0; j < 4; j++) bfr[j] = *(const sh8*)&Bl[brow + j * 1024 + ck];
      // C^T: D[m=Ccol][n=Crow]; A-op = B-tile frag, B-op = A-tile frag
#pragma unroll
      for (int i = 0; i < 4; i++)
#pragma unroll
        for (int j = 0; j < 4; j++) acc[i][j] = MFMA16(bfr[j], af[i], acc[i][j]);
    }
  }

  // C^T epilogue (16x16 C/D map: col=lane&15, row=(lane>>4)*4+reg):
  // lane holds C-row = m0+wm+i*16+l15; C-cols = n0+wn+j*16 + quad*4 + 0..3
#pragma unroll
  for (int i = 0; i < 4; i++) {
    const int row = m0 + wm + i * 16 + l15;
    const bool ok = row < M;
#pragma unroll
    for (int j = 0; j < 4; j++) {
      const int col0 = n0 + wn + j * 16 + quad * 4;
      if (MODE == 0) {
        uint2 pk;
        pk.x = pk_bf16(acc[i][j][0], acc[i][j][1]);
        pk.y = pk_bf16(acc[i][j][2], acc[i][j][3]);
        if (ok) *(uint2*)&Cb[(size_t)row * N + col0] = pk;
      } else {
        const float4 b4 = *(const float4*)&bias[col0];
        float4 v;
        v.x = acc[i][j][0] + b4.x; v.y = acc[i][j][1] + b4.y;
        v.z = acc[i][j][2] + b4.z; v.w = acc[i][j][3] + b4.w;
        if (ok) *(float4*)&Cf[(size_t)row * N + col0] = v;
      }
    }
  }
}

// ---------------- transpose V: QKV[.,2048+h*64+d] -> Vt[(bh*64+d)][s], zero-padded ----------------
__global__ __launch_bounds__(256)
void transpose_v(const ushort* __restrict__ QKV, ushort* __restrict__ Vtg) {
  __shared__ ushort T[64 * 72];
  const int tid = threadIdx.x;
  const int st = blockIdx.x, bh = blockIdx.y;
  const int b = bh >> 4, h = bh & 15;
  const int sr = tid >> 3;          // 0..31
  const int sc = (tid & 7) * 8;     // d-chunk
#pragma unroll
  for (int p = 0; p < 64; p += 32) {
    const int s = st * 64 + p + sr;
    uint4 d = uint4{0u, 0u, 0u, 0u};
    if (s < SS) d = *(const uint4*)(QKV + ((size_t)b * SS + s) * 3072 + 2048 + h * 64 + sc);
    *(uint4*)&T[(p + sr) * 72 + sc] = d;
  }
  __syncthreads();
  const int dd = tid >> 2;          // 0..63
  const int s16 = (tid & 3) * 16;
  sh8 v0, v1;
#pragma unroll
  for (int j = 0; j < 8; j++) v0[j] = (short)T[(s16 + j) * 72 + dd];
#pragma unroll
  for (int j = 0; j < 8; j++) v1[j] = (short)T[(s16 + 8 + j) * 72 + dd];
  ushort* outp = Vtg + ((size_t)bh * 64 + dd) * SPAD + st * 64 + s16;
  *(sh8*)outp = v0;
  *(sh8*)(outp + 8) = v1;
}

// ---------------- flash attention (one-pass softmax, 32 q-rows/wave) -------------
// grid: (5 qblocks of 128, 512 bh). K/V staged via gld16 into swizzled 64-stride
// tiles; each wave reuses K/V frags across 2 q-groups of 16.
// S^T = K·Q^T; O^T = V^T·P^T; l = ones·P^T (all MFMA, no shuffles).
__global__ __launch_bounds__(256)
void flash_attn(const ushort* __restrict__ QKV, const ushort* __restrict__ Vtg,
                ushort* __restrict__ Ob) {
  __shared__ ushort Kl[64 * 64];    // row = kpos, chunk-swizzled
  __shared__ ushort Vl[64 * 64];    // row = d,    chunk-swizzled
  __shared__ ushort Pl[128 * 72];   // row = q (wave-local 32 rows), col = kpos
  const int tid = threadIdx.x;
  const int lane = tid & 63, w = tid >> 6;
  const int l15 = lane & 15, quad = lane >> 4;
  const int qb = blockIdx.x, bh = blockIdx.y;
  const int b = bh >> 4, h = bh & 15;

  sh8 qf[2][2];
#pragma unroll
  for (int g = 0; g < 2; g++) {
    const int qr = qb * 128 + w * 32 + g * 16 + l15;
    const ushort* qrow = QKV + ((size_t)b * SS + min(qr, SS - 1)) * 3072 + h * 64;
    qf[g][0] = *(const sh8*)(qrow + quad * 8);
    qf[g][1] = *(const sh8*)(qrow + 32 + quad * 8);
  }

  sh8 ones;
#pragma unroll
  for (int j = 0; j < 8; j++) ones[j] = (short)0x3F80;   // bf16 1.0

  f32x4 o[2][4];
  f32x4 acc_l[2];
#pragma unroll
  for (int g = 0; g < 2; g++) {
    acc_l[g] = f32x4{0.f, 0.f, 0.f, 0.f};
#pragma unroll
    for (int t = 0; t < 4; t++) o[g][t] = f32x4{0.f, 0.f, 0.f, 0.f};
  }

  // staging: 2 gld16 per matrix; unit u = i*256+tid, row=u>>3, cc=u&7, swizzled source
  const int r0 = tid >> 3;                           // 0..31
  const int swzs = ((tid & 7) ^ (r0 & 7)) * 8;
  const ushort* Kg = QKV + (size_t)b * SS * 3072 + 1024 + h * 64 + swzs;
  const ushort* Vg0 = Vtg + ((size_t)bh * 64 + r0) * SPAD + swzs;
  const ushort* Vg1 = Vtg + ((size_t)bh * 64 + 32 + r0) * SPAD + swzs;
  ushort* lK0 = &Kl[tid * 8];
  ushort* lK1 = &Kl[(256 + tid) * 8];
  ushort* lV0 = &Vl[tid * 8];
  ushort* lV1 = &Vl[(256 + tid) * 8];

  const int swz = l15 & 7;
  const int ca0 = (quad ^ swz) * 8;
  const int ca1 = ((quad + 4) ^ swz) * 8;
  ushort* plw[2] = { &Pl[(w * 32 + l15) * 72], &Pl[(w * 32 + 16 + l15) * 72] };

  for (int kt = 0; kt < 10; kt++) {
    const int kb = kt * 64;
    __syncthreads();
    gld16(Kg + (size_t)min(kb + r0, SS - 1) * 3072, lK0);
    gld16(Kg + (size_t)min(kb + 32 + r0, SS - 1) * 3072, lK1);
    gld16(Vg0 + kb, lV0);
    gld16(Vg1 + kb, lV1);
    __syncthreads();

#pragma unroll
    for (int tn = 0; tn < 4; tn++) {
      const int kr = tn * 16 + l15;
      const sh8 k0 = *(const sh8*)&Kl[kr * 64 + ca0];
      const sh8 k1 = *(const sh8*)&Kl[kr * 64 + ca1];
#pragma unroll
      for (int g = 0; g < 2; g++) {
        f32x4 s = f32x4{0.f, 0.f, 0.f, 0.f};
        s = MFMA16(k0, qf[g][0], s);      // S^T: row=kpos=tn*16+quad*4+r, col=q=l15
        s = MFMA16(k1, qf[g][1], s);
        if (kt == 9) {                    // kb=576: only kpos-local 0 is valid
#pragma unroll
          for (int r = 0; r < 4; r++)
            if ((tn * 16 + quad * 4 + r) != 0) s[r] = -1e30f;
        }
        uint2 pp;
        pp.x = pk_bf16(EXP2F(s[0]), EXP2F(s[1]));
        pp.y = pk_bf16(EXP2F(s[2]), EXP2F(s[3]));
        *(uint2*)(plw[g] + tn * 16 + quad * 4) = pp;
      }
    }
    // wave-local P rows: no barrier needed between write and read
    sh8 pa[2][2];
#pragma unroll
    for (int g = 0; g < 2; g++) {
      pa[g][0] = *(const sh8*)(plw[g] + quad * 8);     // B: n=q=l15, k=kpos
      pa[g][1] = *(const sh8*)(plw[g] + 32 + quad * 8);
      acc_l[g] = MFMA16(ones, pa[g][0], acc_l[g]);
      acc_l[g] = MFMA16(ones, pa[g][1], acc_l[g]);
    }
#pragma unroll
    for (int t = 0; t < 4; t++) {
      const int vr = t * 16 + l15;
      const sh8 v0 = *(const sh8*)&Vl[vr * 64 + ca0];  // A: m=d, k=kpos
      const sh8 v1 = *(const sh8*)&Vl[vr * 64 + ca1];
#pragma unroll
      for (int g = 0; g < 2; g++) {
        o[g][t] = MFMA16(v0, pa[g][0], o[g][t]);       // O^T: row=d, col=q=l15
        o[g][t] = MFMA16(v1, pa[g][1], o[g][t]);
      }
    }
  }

#pragma unroll
  for (int g = 0; g < 2; g++) {
    const float inv = 1.0f / acc_l[g][0];
    const int s = qb * 128 + w * 32 + g * 16 + l15;
    if (s < SS) {
      ushort* op = Ob + ((size_t)b * SS + s) * 1024 + h * 64 + quad * 4;
#pragma unroll
      for (int t = 0; t < 4; t++) {
        uint2 ov;
        ov.x = pk_bf16(o[g][t][0] * inv, o[g][t][1] * inv);
        ov.y = pk_bf16(o[g][t][2] * inv, o[g][t][3] * inv);
        *(uint2*)(op + t * 16) = ov;
      }
    }
  }
}

// ---------------- launch ----------------
extern "C" void kernel_launch(void* const* d_in, const int* in_sizes, int n_in,
                              void* d_out, int out_size, void* d_ws, size_t ws_size,
                              hipStream_t stream) {
  const float* x  = (const float*)d_in[0];
  const float* Wq = (const float*)d_in[1];
  const float* Wk = (const float*)d_in[2];
  const float* Wv = (const float*)d_in[3];
  const float* Wo = (const float*)d_in[4];
  const float* bo = (const float*)d_in[5];
  float* out = (float*)d_out;

  // workspace layout (bf16 elements); Ob reuses Xb (dead after GEMM1)
  ushort* Xb  = (ushort*)d_ws;                      // MM*1024
  ushort* Wt  = Xb  + (size_t)MM * 1024;            // 3072*1024
  ushort* Wob = Wt  + (size_t)3072 * 1024;          // 1024*1024
  ushort* QKV = Wob + (size_t)1024 * 1024;          // MM*3072
  ushort* Vtg = QKV + (size_t)MM * 3072;            // 512*64*640
  ushort* Ob  = Xb;

  convert2_f32_bf16<<<4096, 256, 0, stream>>>(x, Xb, MM * 1024 / 4, Wo, Wob, 1024 * 1024 / 4);
  convert_wqkv<<<dim3(16, 48), 256, 0, stream>>>(Wq, Wk, Wv, Wt);
  gemm_bt<0><<<dim3(24, 145), 256, 0, stream>>>(Xb, Wt, QKV, nullptr, nullptr, MM, 3072, 1024);
  transpose_v<<<dim3(10, 512), 256, 0, stream>>>(QKV, Vtg);
  flash_attn<<<dim3(5, 512), 256, 0, stream>>>(QKV, Vtg, Ob);
  gemm_bt<1><<<dim3(8, 145), 256, 0, stream>>>(Ob, Wob, nullptr, out, bo, MM, 1024, 1024);
}

// Round 5
// 439.812 us; speedup vs baseline: 1.0739x; 1.0398x over previous
//
#include <hip/hip_runtime.h>
#include <hip/hip_bf16.h>
#include <stdint.h>

using sh8    = __attribute__((ext_vector_type(8))) short;
using f32x4  = __attribute__((ext_vector_type(4))) float;
using f32x16 = __attribute__((ext_vector_type(16))) float;

#define MFMA16(a, b, c) __builtin_amdgcn_mfma_f32_16x16x32_bf16(a, b, c, 0, 0, 0)
#define EXP2F(x) __builtin_amdgcn_exp2f(x)

static constexpr int BB = 32, SS = 577, HH = 16;
static constexpr int MM = BB * SS;     // 18464 rows (b,s)
static constexpr int SPAD = 640;       // padded S for V^T buffer
// attention scale folded into Wq, in log2 domain: D^-0.5 * log2(e)
static constexpr float QSCALE = 0.18033688011112042f;

__device__ __forceinline__ ushort f2b(float f) {
  union { float f; uint32_t u; } v{f};
  uint32_t r = v.u + 0x7FFFu + ((v.u >> 16) & 1u);   // RNE
  return (ushort)(r >> 16);
}

#if __has_builtin(__builtin_amdgcn_cvt_pk_bf16_f32)
typedef __attribute__((ext_vector_type(2))) __bf16 bf16x2_t;
__device__ __forceinline__ uint32_t pk_bf16(float a, float b) {
  union { bf16x2_t v; uint32_t u; } c;
  c.v = __builtin_amdgcn_cvt_pk_bf16_f32(a, b);
  return c.u;
}
#else
__device__ __forceinline__ uint32_t pk_bf16(float a, float b) {
  return (uint32_t)f2b(a) | ((uint32_t)f2b(b) << 16);
}
#endif

// async global->LDS, 16B per lane. LDS dest is wave-uniform base + lane*16.
__device__ __forceinline__ void gld16(const ushort* g, ushort* l) {
  __builtin_amdgcn_global_load_lds(
      (const __attribute__((address_space(1))) uint32_t*)g,
      (__attribute__((address_space(3))) uint32_t*)l, 16, 0, 0);
}

// ---------------- converts (x and Wo fused in one launch) ----------------
__global__ __launch_bounds__(256)
void convert2_f32_bf16(const float* __restrict__ a, ushort* __restrict__ oa, int na4,
                       const float* __restrict__ b, ushort* __restrict__ ob, int nb4) {
  const int total = na4 + nb4;
  const int stride = gridDim.x * 256;
  for (int i = blockIdx.x * 256 + threadIdx.x; i < total; i += stride) {
    const float4 f = (i < na4) ? ((const float4*)a)[i] : ((const float4*)b)[i - na4];
    ushort4 u;
    u.x = f2b(f.x); u.y = f2b(f.y); u.z = f2b(f.z); u.w = f2b(f.w);
    if (i < na4) ((ushort4*)oa)[i] = u;
    else         ((ushort4*)ob)[i - na4] = u;
  }
}

// Wt[n][k], n = sel*1024 + h*64 + d  (B^T layout), k = e.  LDS-tiled transpose.
// Wq gets QSCALE folded in. grid (16 ktiles, 48 sel*h).
__global__ __launch_bounds__(256)
void convert_wqkv(const float* __restrict__ Wq, const float* __restrict__ Wk,
                  const float* __restrict__ Wv, ushort* __restrict__ Wt) {
  __shared__ ushort T[64 * 72];
  const int tid = threadIdx.x;
  const int kt = blockIdx.x, sh = blockIdx.y;
  const int sel = sh >> 4, h = sh & 15;
  const float* W = (sel == 0) ? Wq : ((sel == 1) ? Wk : Wv);
  const float qs = (sel == 0) ? QSCALE : 1.0f;
  const int rr = tid >> 4;          // 0..15 (k' row)
  const int rc = (tid & 15) * 4;    // d col (float4)
#pragma unroll
  for (int p = 0; p < 64; p += 16) {
    const float4 f = *(const float4*)(W + (size_t)h * 65536 + (size_t)(kt * 64 + p + rr) * 64 + rc);
    ushort4 u;
    u.x = f2b(f.x * qs); u.y = f2b(f.y * qs); u.z = f2b(f.z * qs); u.w = f2b(f.w * qs);
    *(ushort4*)&T[(p + rr) * 72 + rc] = u;
  }
  __syncthreads();
  const int dd = tid >> 2;          // 0..63 (d)
  const int c16 = (tid & 3) * 16;   // k' base
  sh8 v0, v1;
#pragma unroll
  for (int j = 0; j < 8; j++) v0[j] = (short)T[(c16 + j) * 72 + dd];
#pragma unroll
  for (int j = 0; j < 8; j++) v1[j] = (short)T[(c16 + 8 + j) * 72 + dd];
  ushort* op = Wt + ((size_t)sel * 1024 + h * 64 + dd) * 1024 + kt * 64 + c16;
  *(sh8*)op = v0;
  *(sh8*)(op + 8) = v1;
}

// ---------------- GEMM: 128x128 block, 4 waves, 64x64 wave tile as 4x4 grid
// of 16x16x32 MFMA (16-row fragment reads -> 2-way LDS aliasing = free).
// m97 2-barrier schedule, 32 KB LDS, multi-block/CU residency (m114).
// XCD-chunked block swizzle (nwg % 8 == 0 for both launches): the 24 (resp 8)
// n-blocks sharing one A-panel land on the SAME XCD -> A-panel L2 reuse,
// cutting the ~4x A re-fetch seen as FETCH_SIZE=162MB. C^T trick.
// MODE 0: store bf16.  MODE 1: store f32 + bias.
template <int MODE>
__global__ __launch_bounds__(256)
void gemm_bt(const ushort* __restrict__ A, const ushort* __restrict__ Bt,
             ushort* __restrict__ Cb, float* __restrict__ Cf,
             const float* __restrict__ bias, int M, int N, int K) {
  __shared__ ushort Al[128 * 64];   // 16 KB
  __shared__ ushort Bl[128 * 64];   // 16 KB
  const int tid = threadIdx.x;
  const int lane = tid & 63, w = tid >> 6;
  const int l15 = lane & 15, quad = lane >> 4;
  const int wm = (w >> 1) * 64, wn = (w & 1) * 64;

  // XCD swizzle: nwg divisible by 8 -> simple chunked remap is bijective.
  const int nwg = gridDim.x * gridDim.y;
  const int orig = blockIdx.y * gridDim.x + blockIdx.x;
  const int wgid = (orig & 7) * (nwg >> 3) + (orig >> 3);
  const int m0 = (wgid / gridDim.x) * 128;
  const int n0 = (wgid % gridDim.x) * 128;

  f32x4 acc[4][4];
#pragma unroll
  for (int i = 0; i < 4; i++)
#pragma unroll
    for (int j = 0; j < 4; j++) acc[i][j] = f32x4{0.f, 0.f, 0.f, 0.f};

  // staging: unit u covers LDS ushorts [u*8, u*8+8); row=u>>3, cc=u&7 (swizzled)
  const int rbase = tid >> 3;                         // 0..31
  const int swzc = ((tid & 7) ^ (rbase & 7)) * 8;     // swizzled source col (ushorts)
  const ushort* Ag[4]; const ushort* Bg[4];
  ushort* lA[4]; ushort* lB[4];
#pragma unroll
  for (int i = 0; i < 4; i++) {
    Ag[i] = A + (size_t)min(m0 + i * 32 + rbase, M - 1) * K + swzc;
    Bg[i] = Bt + (size_t)(n0 + i * 32 + rbase) * K + swzc;
    lA[i] = &Al[(i * 256 + tid) * 8];
    lB[i] = &Bl[(i * 256 + tid) * 8];
  }
  // frag-read offsets: global chunk g of row r lives at LDS chunk g ^ (r&7).
  // 16x16x32 fragment: lane (l15,quad) reads row base+l15 (16-row span, 2-way
  // bank aliasing = free), k-chunk kc: logical chunk = kc*4 + quad.
  const int swz = l15 & 7;
  const int c0 = (quad ^ swz) * 8;               // kc=0: k = quad*8 + 0..7
  const int c1 = ((quad + 4) ^ swz) * 8;         // kc=1: k = 32 + quad*8 + 0..7
  const int arow = (wm + l15) * 64;              // + i*1024 per 16-row m-pos
  const int brow = (wn + l15) * 64;              // + j*1024 per 16-row n-pos

  for (int k0 = 0; k0 < K; k0 += 64) {
    __syncthreads();
#pragma unroll
    for (int i = 0; i < 4; i++) {
      gld16(Ag[i] + k0, lA[i]);
      gld16(Bg[i] + k0, lB[i]);
    }
    __syncthreads();
#pragma unroll
    for (int kc = 0; kc < 2; kc++) {
      const int ck = (kc == 0) ? c0 : c1;
      sh8 af[4], bfr[4];
#pragma unroll
      for (int i = 0; i < 4; i++) af[i] = *(const sh8*)&Al[arow + i * 1024 + ck];
#pragma unroll
      for (int j = 0; j < 4; j++) bfr[j] = *(const sh8*)&Bl[brow + j * 1024 + ck];
      // C^T: D[m=Ccol][n=Crow]; A-op = B-tile frag, B-op = A-tile frag
#pragma unroll
      for (int i = 0; i < 4; i++)
#pragma unroll
        for (int j = 0; j < 4; j++) acc[i][j] = MFMA16(bfr[j], af[i], acc[i][j]);
    }
  }

  // C^T epilogue (16x16 C/D map: col=lane&15, row=(lane>>4)*4+reg):
  // lane holds C-row = m0+wm+i*16+l15; C-cols = n0+wn+j*16 + quad*4 + 0..3
#pragma unroll
  for (int i = 0; i < 4; i++) {
    const int row = m0 + wm + i * 16 + l15;
    const bool ok = row < M;
#pragma unroll
    for (int j = 0; j < 4; j++) {
      const int col0 = n0 + wn + j * 16 + quad * 4;
      if (MODE == 0) {
        uint2 pk;
        pk.x = pk_bf16(acc[i][j][0], acc[i][j][1]);
        pk.y = pk_bf16(acc[i][j][2], acc[i][j][3]);
        if (ok) *(uint2*)&Cb[(size_t)row * N + col0] = pk;
      } else {
        const float4 b4 = *(const float4*)&bias[col0];
        float4 v;
        v.x = acc[i][j][0] + b4.x; v.y = acc[i][j][1] + b4.y;
        v.z = acc[i][j][2] + b4.z; v.w = acc[i][j][3] + b4.w;
        if (ok) *(float4*)&Cf[(size_t)row * N + col0] = v;
      }
    }
  }
}

// ---------------- transpose V: QKV[.,2048+h*64+d] -> Vt[(bh*64+d)][s], zero-padded ----------------
__global__ __launch_bounds__(256)
void transpose_v(const ushort* __restrict__ QKV, ushort* __restrict__ Vtg) {
  __shared__ ushort T[64 * 72];
  const int tid = threadIdx.x;
  const int st = blockIdx.x, bh = blockIdx.y;
  const int b = bh >> 4, h = bh & 15;
  const int sr = tid >> 3;          // 0..31
  const int sc = (tid & 7) * 8;     // d-chunk
#pragma unroll
  for (int p = 0; p < 64; p += 32) {
    const int s = st * 64 + p + sr;
    uint4 d = uint4{0u, 0u, 0u, 0u};
    if (s < SS) d = *(const uint4*)(QKV + ((size_t)b * SS + s) * 3072 + 2048 + h * 64 + sc);
    *(uint4*)&T[(p + sr) * 72 + sc] = d;
  }
  __syncthreads();
  const int dd = tid >> 2;          // 0..63
  const int s16 = (tid & 3) * 16;
  sh8 v0, v1;
#pragma unroll
  for (int j = 0; j < 8; j++) v0[j] = (short)T[(s16 + j) * 72 + dd];
#pragma unroll
  for (int j = 0; j < 8; j++) v1[j] = (short)T[(s16 + 8 + j) * 72 + dd];
  ushort* outp = Vtg + ((size_t)bh * 64 + dd) * SPAD + st * 64 + s16;
  *(sh8*)outp = v0;
  *(sh8*)(outp + 8) = v1;
}

// ---------------- flash attention (one-pass softmax, 32 q-rows/wave) -------------
// grid: (5 qblocks of 128, 512 bh). K/V double-buffered in LDS: stage tile
// t+1 BEFORE computing tile t, one __syncthreads per tile (its implicit
// vmcnt(0) drain lands after ~500cy of compute -> staging latency hidden;
// previously the drain immediately followed the issue = full latency stall).
// Pl is wave-local (no cross-wave hazard). Kl/Vl writes always target the
// buffer opposite to all concurrent reads; the end-of-tile barrier keeps the
// re-stage of a buffer after all waves finished reading it.
// S^T = K·Q^T; O^T = V^T·P^T; l = ones·P^T (all MFMA, no shuffles).
__global__ __launch_bounds__(256)
void flash_attn(const ushort* __restrict__ QKV, const ushort* __restrict__ Vtg,
                ushort* __restrict__ Ob) {
  __shared__ ushort Kl[2][64 * 64]; // row = kpos, chunk-swizzled (8 KB each)
  __shared__ ushort Vl[2][64 * 64]; // row = d,    chunk-swizzled
  __shared__ ushort Pl[128 * 72];   // row = q (wave-local 32 rows), col = kpos
  const int tid = threadIdx.x;
  const int lane = tid & 63, w = tid >> 6;
  const int l15 = lane & 15, quad = lane >> 4;
  const int qb = blockIdx.x, bh = blockIdx.y;
  const int b = bh >> 4, h = bh & 15;

  sh8 qf[2][2];
#pragma unroll
  for (int g = 0; g < 2; g++) {
    const int qr = qb * 128 + w * 32 + g * 16 + l15;
    const ushort* qrow = QKV + ((size_t)b * SS + min(qr, SS - 1)) * 3072 + h * 64;
    qf[g][0] = *(const sh8*)(qrow + quad * 8);
    qf[g][1] = *(const sh8*)(qrow + 32 + quad * 8);
  }

  sh8 ones;
#pragma unroll
  for (int j = 0; j < 8; j++) ones[j] = (short)0x3F80;   // bf16 1.0

  f32x4 o[2][4];
  f32x4 acc_l[2];
#pragma unroll
  for (int g = 0; g < 2; g++) {
    acc_l[g] = f32x4{0.f, 0.f, 0.f, 0.f};
#pragma unroll
    for (int t = 0; t < 4; t++) o[g][t] = f32x4{0.f, 0.f, 0.f, 0.f};
  }

  // staging: 2 gld16 per matrix; unit u = i*256+tid, row=u>>3, cc=u&7, swizzled source
  const int r0 = tid >> 3;                           // 0..31
  const int swzs = ((tid & 7) ^ (r0 & 7)) * 8;
  const ushort* Kg = QKV + (size_t)b * SS * 3072 + 1024 + h * 64 + swzs;
  const ushort* Vg0 = Vtg + ((size_t)bh * 64 + r0) * SPAD + swzs;
  const ushort* Vg1 = Vtg + ((size_t)bh * 64 + 32 + r0) * SPAD + swzs;
  ushort* lK0[2] = { &Kl[0][tid * 8],         &Kl[1][tid * 8] };
  ushort* lK1[2] = { &Kl[0][(256 + tid) * 8], &Kl[1][(256 + tid) * 8] };
  ushort* lV0[2] = { &Vl[0][tid * 8],         &Vl[1][tid * 8] };
  ushort* lV1[2] = { &Vl[0][(256 + tid) * 8], &Vl[1][(256 + tid) * 8] };

  const int swz = l15 & 7;
  const int ca0 = (quad ^ swz) * 8;
  const int ca1 = ((quad + 4) ^ swz) * 8;
  ushort* plw[2] = { &Pl[(w * 32 + l15) * 72], &Pl[(w * 32 + 16 + l15) * 72] };

  // prologue: stage tile 0 into buffer 0
  gld16(Kg + (size_t)min(r0, SS - 1) * 3072, lK0[0]);
  gld16(Kg + (size_t)min(32 + r0, SS - 1) * 3072, lK1[0]);
  gld16(Vg0, lV0[0]);
  gld16(Vg1, lV1[0]);
  __syncthreads();

  for (int kt = 0; kt < 10; kt++) {
    const int cur = kt & 1;
    if (kt < 9) {                       // prefetch tile kt+1 into other buffer
      const int kb1 = (kt + 1) * 64;
      gld16(Kg + (size_t)min(kb1 + r0, SS - 1) * 3072, lK0[cur ^ 1]);
      gld16(Kg + (size_t)min(kb1 + 32 + r0, SS - 1) * 3072, lK1[cur ^ 1]);
      gld16(Vg0 + kb1, lV0[cur ^ 1]);
      gld16(Vg1 + kb1, lV1[cur ^ 1]);
    }
    const ushort* Kc = &Kl[cur][0];
    const ushort* Vc = &Vl[cur][0];

#pragma unroll
    for (int tn = 0; tn < 4; tn++) {
      const int kr = tn * 16 + l15;
      const sh8 k0 = *(const sh8*)&Kc[kr * 64 + ca0];
      const sh8 k1 = *(const sh8*)&Kc[kr * 64 + ca1];
#pragma unroll
      for (int g = 0; g < 2; g++) {
        f32x4 s = f32x4{0.f, 0.f, 0.f, 0.f};
        s = MFMA16(k0, qf[g][0], s);      // S^T: row=kpos=tn*16+quad*4+r, col=q=l15
        s = MFMA16(k1, qf[g][1], s);
        if (kt == 9) {                    // kb=576: only kpos-local 0 is valid
#pragma unroll
          for (int r = 0; r < 4; r++)
            if ((tn * 16 + quad * 4 + r) != 0) s[r] = -1e30f;
        }
        uint2 pp;
        pp.x = pk_bf16(EXP2F(s[0]), EXP2F(s[1]));
        pp.y = pk_bf16(EXP2F(s[2]), EXP2F(s[3]));
        *(uint2*)(plw[g] + tn * 16 + quad * 4) = pp;
      }
    }
    // wave-local P rows: no barrier needed between write and read
    sh8 pa[2][2];
#pragma unroll
    for (int g = 0; g < 2; g++) {
      pa[g][0] = *(const sh8*)(plw[g] + quad * 8);     // B: n=q=l15, k=kpos
      pa[g][1] = *(const sh8*)(plw[g] + 32 + quad * 8);
      acc_l[g] = MFMA16(ones, pa[g][0], acc_l[g]);
      acc_l[g] = MFMA16(ones, pa[g][1], acc_l[g]);
    }
#pragma unroll
    for (int t = 0; t < 4; t++) {
      const int vr = t * 16 + l15;
      const sh8 v0 = *(const sh8*)&Vc[vr * 64 + ca0];  // A: m=d, k=kpos
      const sh8 v1 = *(const sh8*)&Vc[vr * 64 + ca1];
#pragma unroll
      for (int g = 0; g < 2; g++) {
        o[g][t] = MFMA16(v0, pa[g][0], o[g][t]);       // O^T: row=d, col=q=l15
        o[g][t] = MFMA16(v1, pa[g][1], o[g][t]);
      }
    }

    if (kt < 9) __syncthreads();        // implicit vmcnt(0): prefetch landed;
                                        // all waves done reading buf 'cur'
  }

#pragma unroll
  for (int g = 0; g < 2; g++) {
    const float inv = 1.0f / acc_l[g][0];
    const int s = qb * 128 + w * 32 + g * 16 + l15;
    if (s < SS) {
      ushort* op = Ob + ((size_t)b * SS + s) * 1024 + h * 64 + quad * 4;
#pragma unroll
      for (int t = 0; t < 4; t++) {
        uint2 ov;
        ov.x = pk_bf16(o[g][t][0] * inv, o[g][t][1] * inv);
        ov.y = pk_bf16(o[g][t][2] * inv, o[g][t][3] * inv);
        *(uint2*)(op + t * 16) = ov;
      }
    }
  }
}

// ---------------- launch ----------------
extern "C" void kernel_launch(void* const* d_in, const int* in_sizes, int n_in,
                              void* d_out, int out_size, void* d_ws, size_t ws_size,
                              hipStream_t stream) {
  const float* x  = (const float*)d_in[0];
  const float* Wq = (const float*)d_in[1];
  const float* Wk = (const float*)d_in[2];
  const float* Wv = (const float*)d_in[3];
  const float* Wo = (const float*)d_in[4];
  const float* bo = (const float*)d_in[5];
  float* out = (float*)d_out;

  // workspace layout (bf16 elements); Ob reuses Xb (dead after GEMM1)
  ushort* Xb  = (ushort*)d_ws;                      // MM*1024
  ushort* Wt  = Xb  + (size_t)MM * 1024;            // 3072*1024
  ushort* Wob = Wt  + (size_t)3072 * 1024;          // 1024*1024
  ushort* QKV = Wob + (size_t)1024 * 1024;          // MM*3072
  ushort* Vtg = QKV + (size_t)MM * 3072;            // 512*64*640
  ushort* Ob  = Xb;

  convert2_f32_bf16<<<4096, 256, 0, stream>>>(x, Xb, MM * 1024 / 4, Wo, Wob, 1024 * 1024 / 4);
  convert_wqkv<<<dim3(16, 48), 256, 0, stream>>>(Wq, Wk, Wv, Wt);
  gemm_bt<0><<<dim3(24, 145), 256, 0, stream>>>(Xb, Wt, QKV, nullptr, nullptr, MM, 3072, 1024);
  transpose_v<<<dim3(10, 512), 256, 0, stream>>>(QKV, Vtg);
  flash_attn<<<dim3(5, 512), 256, 0, stream>>>(QKV, Vtg, Ob);
  gemm_bt<1><<<dim3(8, 145), 256, 0, stream>>>(Ob, Wob, nullptr, out, bo, MM, 1024, 1024);
}

// Round 7
// 426.089 us; speedup vs baseline: 1.1085x; 1.0322x over previous
//
#include <hip/hip_runtime.h>
#include <hip/hip_bf16.h>
#include <stdint.h>

using sh8    = __attribute__((ext_vector_type(8))) short;
using f32x4  = __attribute__((ext_vector_type(4))) float;
using f32x16 = __attribute__((ext_vector_type(16))) float;

#define MFMA16(a, b, c) __builtin_amdgcn_mfma_f32_16x16x32_bf16(a, b, c, 0, 0, 0)
#define EXP2F(x) __builtin_amdgcn_exp2f(x)
#define PRIO1() __builtin_amdgcn_s_setprio(1)
#define PRIO0() __builtin_amdgcn_s_setprio(0)

static constexpr int BB = 32, SS = 577, HH = 16;
static constexpr int MM = BB * SS;     // 18464 rows (b,s)
static constexpr int SPAD = 640;       // padded S for V^T buffer
// attention scale folded into Wq, in log2 domain: D^-0.5 * log2(e)
static constexpr float QSCALE = 0.18033688011112042f;

__device__ __forceinline__ ushort f2b(float f) {
  union { float f; uint32_t u; } v{f};
  uint32_t r = v.u + 0x7FFFu + ((v.u >> 16) & 1u);   // RNE
  return (ushort)(r >> 16);
}

__device__ __forceinline__ float bf2f(ushort u) {
  union { uint32_t u; float f; } v{(uint32_t)u << 16};
  return v.f;
}

#if __has_builtin(__builtin_amdgcn_cvt_pk_bf16_f32)
typedef __attribute__((ext_vector_type(2))) __bf16 bf16x2_t;
__device__ __forceinline__ uint32_t pk_bf16(float a, float b) {
  union { bf16x2_t v; uint32_t u; } c;
  c.v = __builtin_amdgcn_cvt_pk_bf16_f32(a, b);
  return c.u;
}
#else
__device__ __forceinline__ uint32_t pk_bf16(float a, float b) {
  return (uint32_t)f2b(a) | ((uint32_t)f2b(b) << 16);
}
#endif

// async global->LDS, 16B per lane. LDS dest is wave-uniform base + lane*16.
__device__ __forceinline__ void gld16(const ushort* g, ushort* l) {
  __builtin_amdgcn_global_load_lds(
      (const __attribute__((address_space(1))) uint32_t*)g,
      (__attribute__((address_space(3))) uint32_t*)l, 16, 0, 0);
}

// ---------------- converts (x and Wo fused in one launch) ----------------
__global__ __launch_bounds__(256)
void convert2_f32_bf16(const float* __restrict__ a, ushort* __restrict__ oa, int na4,
                       const float* __restrict__ b, ushort* __restrict__ ob, int nb4) {
  const int total = na4 + nb4;
  const int stride = gridDim.x * 256;
  for (int i = blockIdx.x * 256 + threadIdx.x; i < total; i += stride) {
    const float4 f = (i < na4) ? ((const float4*)a)[i] : ((const float4*)b)[i - na4];
    ushort4 u;
    u.x = f2b(f.x); u.y = f2b(f.y); u.z = f2b(f.z); u.w = f2b(f.w);
    if (i < na4) ((ushort4*)oa)[i] = u;
    else         ((ushort4*)ob)[i - na4] = u;
  }
}

// Wt[n][k], n = sel*1024 + h*64 + d  (B^T layout), k = e.  LDS-tiled transpose.
// Wq gets QSCALE folded in. grid (16 ktiles, 48 sel*h).
__global__ __launch_bounds__(256)
void convert_wqkv(const float* __restrict__ Wq, const float* __restrict__ Wk,
                  const float* __restrict__ Wv, ushort* __restrict__ Wt) {
  __shared__ ushort T[64 * 72];
  const int tid = threadIdx.x;
  const int kt = blockIdx.x, sh = blockIdx.y;
  const int sel = sh >> 4, h = sh & 15;
  const float* W = (sel == 0) ? Wq : ((sel == 1) ? Wk : Wv);
  const float qs = (sel == 0) ? QSCALE : 1.0f;
  const int rr = tid >> 4;          // 0..15 (k' row)
  const int rc = (tid & 15) * 4;    // d col (float4)
#pragma unroll
  for (int p = 0; p < 64; p += 16) {
    const float4 f = *(const float4*)(W + (size_t)h * 65536 + (size_t)(kt * 64 + p + rr) * 64 + rc);
    ushort4 u;
    u.x = f2b(f.x * qs); u.y = f2b(f.y * qs); u.z = f2b(f.z * qs); u.w = f2b(f.w * qs);
    *(ushort4*)&T[(p + rr) * 72 + rc] = u;
  }
  __syncthreads();
  const int dd = tid >> 2;          // 0..63 (d)
  const int c16 = (tid & 3) * 16;   // k' base
  sh8 v0, v1;
#pragma unroll
  for (int j = 0; j < 8; j++) v0[j] = (short)T[(c16 + j) * 72 + dd];
#pragma unroll
  for (int j = 0; j < 8; j++) v1[j] = (short)T[(c16 + 8 + j) * 72 + dd];
  ushort* op = Wt + ((size_t)sel * 1024 + h * 64 + dd) * 1024 + kt * 64 + c16;
  *(sh8*)op = v0;
  *(sh8*)(op + 8) = v1;
}

// ---------------- GEMM: 128x128 block, 4 waves, 64x64 wave tile as 4x4 grid
// of 16x16x32 MFMA (16-row fragment reads -> 2-way LDS aliasing = free).
// m97 2-barrier schedule, 32 KB LDS, multi-block/CU residency (m114).
// NO XCD swizzle: measured FETCH 162->226MB and dur 148->151 with chunked
// remap (B=6MB > 4MB per-XCD L2 -> swizzle destroys implicit B sharing).
// C^T trick. MODE 0: store bf16.  MODE 1: store f32 + bias.
template <int MODE>
__global__ __launch_bounds__(256)
void gemm_bt(const ushort* __restrict__ A, const ushort* __restrict__ Bt,
             ushort* __restrict__ Cb, float* __restrict__ Cf,
             const float* __restrict__ bias, int M, int N, int K) {
  __shared__ ushort Al[128 * 64];   // 16 KB
  __shared__ ushort Bl[128 * 64];   // 16 KB
  const int tid = threadIdx.x;
  const int lane = tid & 63, w = tid >> 6;
  const int l15 = lane & 15, quad = lane >> 4;
  const int wm = (w >> 1) * 64, wn = (w & 1) * 64;
  const int m0 = blockIdx.y * 128, n0 = blockIdx.x * 128;

  f32x4 acc[4][4];
#pragma unroll
  for (int i = 0; i < 4; i++)
#pragma unroll
    for (int j = 0; j < 4; j++) acc[i][j] = f32x4{0.f, 0.f, 0.f, 0.f};

  // staging: unit u covers LDS ushorts [u*8, u*8+8); row=u>>3, cc=u&7 (swizzled)
  const int rbase = tid >> 3;                         // 0..31
  const int swzc = ((tid & 7) ^ (rbase & 7)) * 8;     // swizzled source col (ushorts)
  const ushort* Ag[4]; const ushort* Bg[4];
  ushort* lA[4]; ushort* lB[4];
#pragma unroll
  for (int i = 0; i < 4; i++) {
    Ag[i] = A + (size_t)min(m0 + i * 32 + rbase, M - 1) * K + swzc;
    Bg[i] = Bt + (size_t)(n0 + i * 32 + rbase) * K + swzc;
    lA[i] = &Al[(i * 256 + tid) * 8];
    lB[i] = &Bl[(i * 256 + tid) * 8];
  }
  // frag-read offsets: global chunk g of row r lives at LDS chunk g ^ (r&7).
  // 16x16x32 fragment: lane (l15,quad) reads row base+l15 (16-row span, 2-way
  // bank aliasing = free), k-chunk kc: logical chunk = kc*4 + quad.
  const int swz = l15 & 7;
  const int c0 = (quad ^ swz) * 8;               // kc=0: k = quad*8 + 0..7
  const int c1 = ((quad + 4) ^ swz) * 8;         // kc=1: k = 32 + quad*8 + 0..7
  const int arow = (wm + l15) * 64;              // + i*1024 per 16-row m-pos
  const int brow = (wn + l15) * 64;              // + j*1024 per 16-row n-pos

  for (int k0 = 0; k0 < K; k0 += 64) {
    __syncthreads();
#pragma unroll
    for (int i = 0; i < 4; i++) {
      gld16(Ag[i] + k0, lA[i]);
      gld16(Bg[i] + k0, lB[i]);
    }
    __syncthreads();
#pragma unroll
    for (int kc = 0; kc < 2; kc++) {
      const int ck = (kc == 0) ? c0 : c1;
      sh8 af[4], bfr[4];
#pragma unroll
      for (int i = 0; i < 4; i++) af[i] = *(const sh8*)&Al[arow + i * 1024 + ck];
#pragma unroll
      for (int j = 0; j < 4; j++) bfr[j] = *(const sh8*)&Bl[brow + j * 1024 + ck];
      // C^T: D[m=Ccol][n=Crow]; A-op = B-tile frag, B-op = A-tile frag
#pragma unroll
      for (int i = 0; i < 4; i++)
#pragma unroll
        for (int j = 0; j < 4; j++) acc[i][j] = MFMA16(bfr[j], af[i], acc[i][j]);
    }
  }

  // C^T epilogue (16x16 C/D map: col=lane&15, row=(lane>>4)*4+reg):
  // lane holds C-row = m0+wm+i*16+l15; C-cols = n0+wn+j*16 + quad*4 + 0..3
#pragma unroll
  for (int i = 0; i < 4; i++) {
    const int row = m0 + wm + i * 16 + l15;
    const bool ok = row < M;
#pragma unroll
    for (int j = 0; j < 4; j++) {
      const int col0 = n0 + wn + j * 16 + quad * 4;
      if (MODE == 0) {
        uint2 pk;
        pk.x = pk_bf16(acc[i][j][0], acc[i][j][1]);
        pk.y = pk_bf16(acc[i][j][2], acc[i][j][3]);
        if (ok) *(uint2*)&Cb[(size_t)row * N + col0] = pk;
      } else {
        const float4 b4 = *(const float4*)&bias[col0];
        float4 v;
        v.x = acc[i][j][0] + b4.x; v.y = acc[i][j][1] + b4.y;
        v.z = acc[i][j][2] + b4.z; v.w = acc[i][j][3] + b4.w;
        if (ok) *(float4*)&Cf[(size_t)row * N + col0] = v;
      }
    }
  }
}

// ---------------- transpose V: QKV[.,2048+h*64+d] -> Vt[(bh*64+d)][s], zero-padded ----------------
__global__ __launch_bounds__(256)
void transpose_v(const ushort* __restrict__ QKV, ushort* __restrict__ Vtg) {
  __shared__ ushort T[64 * 72];
  const int tid = threadIdx.x;
  const int st = blockIdx.x, bh = blockIdx.y;
  const int b = bh >> 4, h = bh & 15;
  const int sr = tid >> 3;          // 0..31
  const int sc = (tid & 7) * 8;     // d-chunk
#pragma unroll
  for (int p = 0; p < 64; p += 32) {
    const int s = st * 64 + p + sr;
    uint4 d = uint4{0u, 0u, 0u, 0u};
    if (s < SS) d = *(const uint4*)(QKV + ((size_t)b * SS + s) * 3072 + 2048 + h * 64 + sc);
    *(uint4*)&T[(p + sr) * 72 + sc] = d;
  }
  __syncthreads();
  const int dd = tid >> 2;          // 0..63
  const int s16 = (tid & 3) * 16;
  sh8 v0, v1;
#pragma unroll
  for (int j = 0; j < 8; j++) v0[j] = (short)T[(s16 + j) * 72 + dd];
#pragma unroll
  for (int j = 0; j < 8; j++) v1[j] = (short)T[(s16 + 8 + j) * 72 + dd];
  ushort* outp = Vtg + ((size_t)bh * 64 + dd) * SPAD + st * 64 + s16;
  *(sh8*)outp = v0;
  *(sh8*)(outp + 8) = v1;
}

// ---------------- flash attention (one-pass softmax, 32 q-rows/wave) -------------
// grid: (5 qblocks of 128, 512 bh). 9 FULL K-tiles (9*64 = 576 kpos, no
// masking, no row clamps) + closed-form VALU tail for kpos=576: previously
// tile 10 burned a full tile pass (36 MFMA + 32 exp/wave) for ONE valid
// column. K/V double-buffered: prefetch t+1 before compute of t, one
// __syncthreads per tile (implicit vmcnt(0) lands after ~500cy of compute).
// Pl is wave-local. setprio(1) around MFMA clusters (T5: +4-7% measured on
// attn-regime kernels; blocks independent, phases staggered).
// S^T = K·Q^T; O^T = V^T·P^T; l = ones·P^T (all MFMA, no shuffles).
__global__ __launch_bounds__(256)
void flash_attn(const ushort* __restrict__ QKV, const ushort* __restrict__ Vtg,
                ushort* __restrict__ Ob) {
  __shared__ ushort Kl[2][64 * 64]; // row = kpos, chunk-swizzled (8 KB each)
  __shared__ ushort Vl[2][64 * 64]; // row = d,    chunk-swizzled
  __shared__ ushort Pl[128 * 72];   // row = q (wave-local 32 rows), col = kpos
  __shared__ ushort vt576[64];      // V row 576 (d = 0..63)
  const int tid = threadIdx.x;
  const int lane = tid & 63, w = tid >> 6;
  const int l15 = lane & 15, quad = lane >> 4;
  const int qb = blockIdx.x, bh = blockIdx.y;
  const int b = bh >> 4, h = bh & 15;

  sh8 qf[2][2];
#pragma unroll
  for (int g = 0; g < 2; g++) {
    const int qr = qb * 128 + w * 32 + g * 16 + l15;
    const ushort* qrow = QKV + ((size_t)b * SS + min(qr, SS - 1)) * 3072 + h * 64;
    qf[g][0] = *(const sh8*)(qrow + quad * 8);
    qf[g][1] = *(const sh8*)(qrow + 32 + quad * 8);
  }

  sh8 ones;
#pragma unroll
  for (int j = 0; j < 8; j++) ones[j] = (short)0x3F80;   // bf16 1.0

  f32x4 o[2][4];
  f32x4 acc_l[2];
#pragma unroll
  for (int g = 0; g < 2; g++) {
    acc_l[g] = f32x4{0.f, 0.f, 0.f, 0.f};
#pragma unroll
    for (int t = 0; t < 4; t++) o[g][t] = f32x4{0.f, 0.f, 0.f, 0.f};
  }

  // staging: 2 gld16 per matrix; unit u = i*256+tid, row=u>>3, cc=u&7, swizzled source
  const int r0 = tid >> 3;                           // 0..31
  const int swzs = ((tid & 7) ^ (r0 & 7)) * 8;
  const ushort* Kg = QKV + (size_t)b * SS * 3072 + 1024 + h * 64 + swzs;
  const ushort* Vg0 = Vtg + ((size_t)bh * 64 + r0) * SPAD + swzs;
  const ushort* Vg1 = Vtg + ((size_t)bh * 64 + 32 + r0) * SPAD + swzs;
  ushort* lK0[2] = { &Kl[0][tid * 8],         &Kl[1][tid * 8] };
  ushort* lK1[2] = { &Kl[0][(256 + tid) * 8], &Kl[1][(256 + tid) * 8] };
  ushort* lV0[2] = { &Vl[0][tid * 8],         &Vl[1][tid * 8] };
  ushort* lV1[2] = { &Vl[0][(256 + tid) * 8], &Vl[1][(256 + tid) * 8] };

  const int swz = l15 & 7;
  const int ca0 = (quad ^ swz) * 8;
  const int ca1 = ((quad + 4) ^ swz) * 8;
  ushort* plw[2] = { &Pl[(w * 32 + l15) * 72], &Pl[(w * 32 + 16 + l15) * 72] };

  // prologue: stage tile 0 into buffer 0; stage V row 576 (coalesced 128B)
  gld16(Kg + (size_t)r0 * 3072, lK0[0]);
  gld16(Kg + (size_t)(32 + r0) * 3072, lK1[0]);
  gld16(Vg0, lV0[0]);
  gld16(Vg1, lV1[0]);
  if (tid < 64) vt576[tid] = QKV[((size_t)b * SS + 576) * 3072 + 2048 + h * 64 + tid];
  __syncthreads();

  for (int kt = 0; kt < 9; kt++) {
    const int cur = kt & 1;
    if (kt < 8) {                       // prefetch tile kt+1 into other buffer
      const int kb1 = (kt + 1) * 64;    // rows kb1..kb1+63 <= 575: no clamps
      gld16(Kg + (size_t)(kb1 + r0) * 3072, lK0[cur ^ 1]);
      gld16(Kg + (size_t)(kb1 + 32 + r0) * 3072, lK1[cur ^ 1]);
      gld16(Vg0 + kb1, lV0[cur ^ 1]);
      gld16(Vg1 + kb1, lV1[cur ^ 1]);
    }
    const ushort* Kc = &Kl[cur][0];
    const ushort* Vc = &Vl[cur][0];

#pragma unroll
    for (int tn = 0; tn < 4; tn++) {
      const int kr = tn * 16 + l15;
      const sh8 k0 = *(const sh8*)&Kc[kr * 64 + ca0];
      const sh8 k1 = *(const sh8*)&Kc[kr * 64 + ca1];
      f32x4 sv[2];
      PRIO1();
#pragma unroll
      for (int g = 0; g < 2; g++) {
        sv[g] = f32x4{0.f, 0.f, 0.f, 0.f};
        sv[g] = MFMA16(k0, qf[g][0], sv[g]);  // S^T: row=kpos=tn*16+quad*4+r, col=q=l15
        sv[g] = MFMA16(k1, qf[g][1], sv[g]);
      }
      PRIO0();
#pragma unroll
      for (int g = 0; g < 2; g++) {
        uint2 pp;
        pp.x = pk_bf16(EXP2F(sv[g][0]), EXP2F(sv[g][1]));
        pp.y = pk_bf16(EXP2F(sv[g][2]), EXP2F(sv[g][3]));
        *(uint2*)(plw[g] + tn * 16 + quad * 4) = pp;
      }
    }
    // wave-local P rows: no barrier needed between write and read
    sh8 pa[2][2];
#pragma unroll
    for (int g = 0; g < 2; g++) {
      pa[g][0] = *(const sh8*)(plw[g] + quad * 8);     // B: n=q=l15, k=kpos
      pa[g][1] = *(const sh8*)(plw[g] + 32 + quad * 8);
    }
    PRIO1();
#pragma unroll
    for (int g = 0; g < 2; g++) {
      acc_l[g] = MFMA16(ones, pa[g][0], acc_l[g]);
      acc_l[g] = MFMA16(ones, pa[g][1], acc_l[g]);
    }
#pragma unroll
    for (int t = 0; t < 4; t++) {
      const int vr = t * 16 + l15;
      const sh8 v0 = *(const sh8*)&Vc[vr * 64 + ca0];  // A: m=d, k=kpos
      const sh8 v1 = *(const sh8*)&Vc[vr * 64 + ca1];
#pragma unroll
      for (int g = 0; g < 2; g++) {
        o[g][t] = MFMA16(v0, pa[g][0], o[g][t]);       // O^T: row=d, col=q=l15
        o[g][t] = MFMA16(v1, pa[g][1], o[g][t]);
      }
    }
    PRIO0();

    if (kt < 8) __syncthreads();        // implicit vmcnt(0): prefetch landed;
                                        // all waves done reading buf 'cur'
  }

  // ---- tail: kpos = 576 (the 577th key), closed-form on VALU ----
  // s[q] = q . k576  (QSCALE already folded into q); p = exp2(s);
  // l += p; O[q][d] += p * V576[d].
  const ushort* k576p = QKV + ((size_t)b * SS + 576) * 3072 + 1024 + h * 64;
  const sh8 kta = *(const sh8*)(k576p + quad * 8);
  const sh8 ktb = *(const sh8*)(k576p + 32 + quad * 8);
  float p5[2];
#pragma unroll
  for (int g = 0; g < 2; g++) {
    float s = 0.f;
#pragma unroll
    for (int j = 0; j < 8; j++) {
      s += bf2f((ushort)qf[g][0][j]) * bf2f((ushort)kta[j]);
      s += bf2f((ushort)qf[g][1][j]) * bf2f((ushort)ktb[j]);
    }
    // reduce over the 4 lanes sharing l15 (quad = 0..3 hold e-chunks)
    s += __shfl_xor(s, 16);
    s += __shfl_xor(s, 32);
    p5[g] = EXP2F(s);
  }
#pragma unroll
  for (int g = 0; g < 2; g++)
#pragma unroll
    for (int t = 0; t < 4; t++)
#pragma unroll
      for (int r = 0; r < 4; r++)
        o[g][t][r] += p5[g] * bf2f(vt576[t * 16 + quad * 4 + r]);

#pragma unroll
  for (int g = 0; g < 2; g++) {
    const float inv = 1.0f / (acc_l[g][0] + p5[g]);
    const int s = qb * 128 + w * 32 + g * 16 + l15;
    if (s < SS) {
      ushort* op = Ob + ((size_t)b * SS + s) * 1024 + h * 64 + quad * 4;
#pragma unroll
      for (int t = 0; t < 4; t++) {
        uint2 ov;
        ov.x = pk_bf16(o[g][t][0] * inv, o[g][t][1] * inv);
        ov.y = pk_bf16(o[g][t][2] * inv, o[g][t][3] * inv);
        *(uint2*)(op + t * 16) = ov;
      }
    }
  }
}

// ---------------- launch ----------------
extern "C" void kernel_launch(void* const* d_in, const int* in_sizes, int n_in,
                              void* d_out, int out_size, void* d_ws, size_t ws_size,
                              hipStream_t stream) {
  const float* x  = (const float*)d_in[0];
  const float* Wq = (const float*)d_in[1];
  const float* Wk = (const float*)d_in[2];
  const float* Wv = (const float*)d_in[3];
  const float* Wo = (const float*)d_in[4];
  const float* bo = (const float*)d_in[5];
  float* out = (float*)d_out;

  // workspace layout (bf16 elements); Ob reuses Xb (dead after GEMM1)
  ushort* Xb  = (ushort*)d_ws;                      // MM*1024
  ushort* Wt  = Xb  + (size_t)MM * 1024;            // 3072*1024
  ushort* Wob = Wt  + (size_t)3072 * 1024;          // 1024*1024
  ushort* QKV = Wob + (size_t)1024 * 1024;          // MM*3072
  ushort* Vtg = QKV + (size_t)MM * 3072;            // 512*64*640
  ushort* Ob  = Xb;

  convert2_f32_bf16<<<4096, 256, 0, stream>>>(x, Xb, MM * 1024 / 4, Wo, Wob, 1024 * 1024 / 4);
  convert_wqkv<<<dim3(16, 48), 256, 0, stream>>>(Wq, Wk, Wv, Wt);
  gemm_bt<0><<<dim3(24, 145), 256, 0, stream>>>(Xb, Wt, QKV, nullptr, nullptr, MM, 3072, 1024);
  transpose_v<<<dim3(10, 512), 256, 0, stream>>>(QKV, Vtg);
  flash_attn<<<dim3(5, 512), 256, 0, stream>>>(QKV, Vtg, Ob);
  gemm_bt<1><<<dim3(8, 145), 256, 0, stream>>>(Ob, Wob, nullptr, out, bo, MM, 1024, 1024);
}